// Round 11
// baseline (3289.091 us; speedup 1.0000x reference)
//
#include <hip/hip_runtime.h>
#include <stdint.h>

// R15 (resubmit; round 10 was GPUAcquisitionTimeout, kernel never ran).
// R15 = R14 (2441us) + third wave per SIMD (768 threads / 12 waves).
// R14 analysis: 36% MFMA / 24% VALU per active CU, ~40% latency stall at
// 2 waves/SIMD. 4-waves (R7/R8) hits the 128-reg cliff; 3 waves gives a
// 170-reg budget (~143 needed). Decomposition: waves 0-7 keep EXACT R14
// roles minus one Y stream (lo: G+j1, hi: G+j2, 72 MFMA); waves 8-11 take
// j3+j4 (96 MFMA). Per SIMD 72+72+96 = 240 = unchanged issue, +1 wave of
// latency hiding. Gates/P2/update/IO/sync/LDS: unchanged, guarded w<8;
// all barriers outside guards. Numerics bit-identical.

typedef short short8 __attribute__((ext_vector_type(8)));
typedef float float4v __attribute__((ext_vector_type(4)));
typedef unsigned short ushort4v __attribute__((ext_vector_type(4)));
typedef unsigned int uint4v __attribute__((ext_vector_type(4)));
typedef unsigned int uint2v __attribute__((ext_vector_type(2)));

#define MF(a,b,c) __builtin_amdgcn_mfma_f32_16x16x32_bf16(a,b,c,0,0,0)

__device__ __forceinline__ unsigned short f2bf(float v){
  unsigned int x = __builtin_bit_cast(unsigned int, v);
  x += 0x7FFFu + ((x >> 16) & 1u);
  return (unsigned short)(x >> 16);
}
__device__ __forceinline__ float bf2f(unsigned short h){
  unsigned int x = ((unsigned int)h) << 16;
  return __builtin_bit_cast(float, x);
}
__device__ __forceinline__ void cvt_hilo(const float4v v, ushort4v& oh, ushort4v& ol){
#pragma unroll
  for (int r=0;r<4;r++){ unsigned short h=f2bf(v[r]); oh[r]=h; ol[r]=f2bf(v[r]-bf2f(h)); }
}

// packed conversion: 2 floats -> 1 u32 of 2xbf16 (T12 recipe; no builtin)
__device__ __forceinline__ unsigned int cvtpk(float a, float b){
  unsigned int r;
  asm("v_cvt_pk_bf16_f32 %0, %1, %2" : "=v"(r) : "v"(a), "v"(b));
  return r;
}
__device__ __forceinline__ float bcf(unsigned int x){
  return __builtin_bit_cast(float, x);
}
__device__ __forceinline__ void cvt_hilo_pk(const float4v v,
    unsigned int& h0, unsigned int& h1, unsigned int& l0, unsigned int& l1){
  h0 = cvtpk(v[0], v[1]);
  h1 = cvtpk(v[2], v[3]);
  l0 = cvtpk(v[0]-bcf(h0<<16), v[1]-bcf(h0&0xffff0000u));
  l1 = cvtpk(v[2]-bcf(h1<<16), v[3]-bcf(h1&0xffff0000u));
}

// ---- LDS (u16). pair planes: hi at base, lo at +PLO; row stride 72 u16 ----
#define PLO 4608
#define XP  0
#define HP  9216
#define RH  18432
#define YS0 27648   // YA sup0 (j1)
#define YS1 36864   // YB sup0 (j2, pre-scaled 2x)
#define YS2 46080   // YA sup1 (j3)
#define YS3 55296   // YB sup1 (j4, pre-scaled 2x)
#define Z0F 32256   // f32 index (u16 64512), stride 68 floats
#define Z1F 36608
#define LDS_BYTES 163840

// ---- ws offsets (u16) ----
#define WSF_S2   16384
#define WSF_WG0  32768
#define WSF_WC0  196608
#define WSF_WG1  278528
#define WSF_WC1  442368
#define WSF_CAP  524288
#define WSF_FLAG 655360   // int flags[32][128]
#define WSF_DONE 663552   // int done[32]
#define WSF_SLOT 663616   // 32*16 slots * 4096 u32 (hi | lo<<16)
#define WSF_SQS  4857920  // 2*4096 f32 scratch (S0^2, S1^2)

#define TB(grp,j,nt) ((((grp)*5+(j))*4+(nt))*4)

__device__ __forceinline__ void store_Y(unsigned short* lds_, int buf, int nt,
                                        int fc, int qd, const float4v* acc){
#pragma unroll
  for (int Mt=0;Mt<4;Mt++){
    unsigned int h0,h1,l0,l1;
    cvt_hilo_pk(acc[Mt],h0,h1,l0,l1);
    const int o = buf + (16*nt+fc)*72 + 16*Mt + 4*qd;   // o%4==0 -> 8B aligned
    uint2v hv; hv[0]=h0; hv[1]=h1;
    uint2v lv; lv[0]=l0; lv[1]=l1;
    *(uint2v*)(lds_+o)=hv; *(uint2v*)(lds_+o+PLO)=lv;
  }
}

__device__ __forceinline__ void xp_write_pk(unsigned short* lds_, int node, int f0,
                                            float4v a0, float4v a1){
  unsigned int h0,h1,h2,h3, l0,l1,l2,l3;
  cvt_hilo_pk(a0, h0,h1, l0,l1);
  cvt_hilo_pk(a1, h2,h3, l2,l3);
  uint4v hv; hv[0]=h0; hv[1]=h1; hv[2]=h2; hv[3]=h3;
  uint4v lv; lv[0]=l0; lv[1]=l1; lv[2]=l2; lv[3]=l3;
  *(uint4v*)(lds_ + XP + node*72 + f0) = hv;        // 16B aligned
  *(uint4v*)(lds_ + XP + PLO + node*72 + f0) = lv;
}

// P1 (12-wave split): waves 0-3: G(Mt0-1) + j1 stream; waves 4-7: G(Mt2-3)
// + j2; waves 8-11: j3 + j4. All wave-group branches are wave-uniform and
// all register indices compile-time (rule #20).
__device__ __forceinline__ void p1_group(unsigned short* lds_,
    const unsigned short* __restrict__ wfr, int grp, int p0, int p1,
    float bias, float4v* gacc, int w, int ln, int fc, int qd)
{
  const int nt = w & 3;
  float4v aY0[4], aY1[4];
#pragma unroll
  for (int Mt=0;Mt<4;Mt++){
    aY0[Mt]=(float4v){0.f,0.f,0.f,0.f};
    aY1[Mt]=(float4v){0.f,0.f,0.f,0.f};
  }
  if (w < 8){
#pragma unroll
    for (int i=0;i<2;i++) gacc[i]=(float4v){bias,bias,bias,bias};
  }
  const int tbG = TB(grp,0,nt);
  const int tbA = (w<4)? TB(grp,1,nt) : (w<8)? TB(grp,2,nt) : TB(grp,3,nt);
  const int tbB = TB(grp,4,nt);    // only waves 8-11
#pragma unroll
  for (int kt=0;kt<4;kt++){
    const int pb = (kt<2)? p0 : p1;
    short8 ah[4], al[4];
#pragma unroll
    for (int Mt=0;Mt<4;Mt++){
      const int o = pb + (16*Mt+fc)*72 + 32*(kt&1) + 8*qd;
      ah[Mt]=*(const short8*)(lds_+o);
      al[Mt]=*(const short8*)(lds_+o+PLO);
    }
    if (w < 8){
      // G stream (2 Mt, compile-time indices per wave-uniform branch)
      {
        const unsigned short* wb = wfr + (size_t)((tbG+kt)*2)*512 + ln*8;
        short8 bh=*(const short8*)wb, bl=*(const short8*)(wb+512);
        if (w < 4){
          gacc[0]=MF(ah[0],bh,gacc[0]); gacc[0]=MF(ah[0],bl,gacc[0]);
          gacc[0]=MF(al[0],bh,gacc[0]);
          gacc[1]=MF(ah[1],bh,gacc[1]); gacc[1]=MF(ah[1],bl,gacc[1]);
          gacc[1]=MF(al[1],bh,gacc[1]);
        } else {
          gacc[0]=MF(ah[2],bh,gacc[0]); gacc[0]=MF(ah[2],bl,gacc[0]);
          gacc[0]=MF(al[2],bh,gacc[0]);
          gacc[1]=MF(ah[3],bh,gacc[1]); gacc[1]=MF(ah[3],bl,gacc[1]);
          gacc[1]=MF(al[3],bh,gacc[1]);
        }
      }
      // single Y stream (j1 or j2)
      {
        const unsigned short* wb = wfr + (size_t)((tbA+kt)*2)*512 + ln*8;
        short8 bh=*(const short8*)wb, bl=*(const short8*)(wb+512);
#pragma unroll
        for (int Mt=0;Mt<4;Mt++){
          aY0[Mt]=MF(ah[Mt],bh,aY0[Mt]); aY0[Mt]=MF(ah[Mt],bl,aY0[Mt]);
          aY0[Mt]=MF(al[Mt],bh,aY0[Mt]);
        }
      }
    } else {
      // two Y streams (j3, j4)
      {
        const unsigned short* wb = wfr + (size_t)((tbA+kt)*2)*512 + ln*8;
        short8 bh=*(const short8*)wb, bl=*(const short8*)(wb+512);
#pragma unroll
        for (int Mt=0;Mt<4;Mt++){
          aY0[Mt]=MF(ah[Mt],bh,aY0[Mt]); aY0[Mt]=MF(ah[Mt],bl,aY0[Mt]);
          aY0[Mt]=MF(al[Mt],bh,aY0[Mt]);
        }
      }
      {
        const unsigned short* wb = wfr + (size_t)((tbB+kt)*2)*512 + ln*8;
        short8 bh=*(const short8*)wb, bl=*(const short8*)(wb+512);
#pragma unroll
        for (int Mt=0;Mt<4;Mt++){
          aY1[Mt]=MF(ah[Mt],bh,aY1[Mt]); aY1[Mt]=MF(ah[Mt],bl,aY1[Mt]);
          aY1[Mt]=MF(al[Mt],bh,aY1[Mt]);
        }
      }
    }
  }
  if (w < 4){
    store_Y(lds_, YS0, nt, fc, qd, aY0);                 // j1
  } else if (w < 8){
    store_Y(lds_, YS1, nt, fc, qd, aY0);                 // j2
  } else {
    store_Y(lds_, YS2, nt, fc, qd, aY0);                 // j3
    store_Y(lds_, YS3, nt, fc, qd, aY1);                 // j4
  }
}

// P2 fused: Z_sup = S_sup @ YA_sup + S_sup^2 @ YB_sup  -> fp32 Z plane
__device__ __forceinline__ void p2_fused(unsigned short* lds_,
    const short8* sfA, const short8* sfB, int sup, int mt, int fc, int qd)
{
  const int ya = sup? YS2 : YS0;
  const int yb = sup? YS3 : YS1;
  float* zf = (float*)lds_ + (sup? Z1F : Z0F);
#pragma unroll
  for (int nt=0;nt<4;nt++){
    float4v acc = {0.f,0.f,0.f,0.f};
#pragma unroll
    for (int kt=0;kt<2;kt++){
      {
        const int bo = ya + (16*nt+fc)*72 + 32*kt + 8*qd;
        short8 bh=*(const short8*)(lds_+bo), bl=*(const short8*)(lds_+bo+PLO);
        acc=MF(sfA[kt*2+0],bh,acc); acc=MF(sfA[kt*2+0],bl,acc); acc=MF(sfA[kt*2+1],bh,acc);
      }
      {
        const int bo = yb + (16*nt+fc)*72 + 32*kt + 8*qd;
        short8 bh=*(const short8*)(lds_+bo), bl=*(const short8*)(lds_+bo+PLO);
        acc=MF(sfB[kt*2+0],bh,acc); acc=MF(sfB[kt*2+0],bl,acc); acc=MF(sfB[kt*2+1],bh,acc);
      }
    }
    *(float4v*)(zf + (16*nt+fc)*68 + 16*mt + 4*qd) = acc;
  }
}

__device__ __forceinline__ void read_pre(const unsigned short* lds_,
    const float4v* gacc, float4v* pre, int mo, int ntg, int fc, int qd)
{
  const float* lf = (const float*)lds_;
#pragma unroll
  for (int i=0;i<2;i++){
    const int Mt = mo+i;
    float4v za = *(const float4v*)(lf + Z0F + (16*ntg+fc)*68 + 16*Mt + 4*qd);
    float4v zb = *(const float4v*)(lf + Z1F + (16*ntg+fc)*68 + 16*Mt + 4*qd);
    pre[i] = gacc[i] + za + zb;
  }
}

__device__ __forceinline__ void scatter_plane(unsigned short* lds_, int plane,
    int mo, int ntg, int fc, int qd, const ushort4v* oh, const ushort4v* ol)
{
#pragma unroll
  for (int i=0;i<2;i++){
#pragma unroll
    for (int r=0;r<4;r++){
      const int o = plane + (16*(mo+i)+4*qd+r)*72 + 16*ntg+fc;
      lds_[o] = oh[i][r]; lds_[o+PLO] = ol[i][r];
    }
  }
}

__global__ void __launch_bounds__(768, 3)
dcrnn_main(const float* __restrict__ input_seq, const int* __restrict__ seq_lengths,
           const float* __restrict__ bg0, const float* __restrict__ bc0,
           const float* __restrict__ bg1, const float* __restrict__ bc1,
           const float* __restrict__ Wp, const float* __restrict__ bp,
           unsigned short* __restrict__ ws, float* __restrict__ out)
{
  extern __shared__ unsigned short lds_[];
  const int tid = threadIdx.x;
  const int w = tid>>6, ln = tid&63, fc = ln&15, qd = ln>>4;
  const int role = blockIdx.x >> 5;   // 0 = layer0 producer, 1 = layer1 consumer
  const int b = blockIdx.x & 31;
  const bool core = (w < 8);          // waves 0-7: P2/gate/update/IO roles

  const unsigned short* frags = ws;
  int* flags = (int*)(ws + WSF_FLAG) + b*128;
  int* done  = (int*)(ws + WSF_DONE) + b;
  unsigned short* capb = ws + WSF_CAP + (size_t)b*4096;
  unsigned int* slots = (unsigned int*)(ws + WSF_SLOT);

  // zero HP pair: u16 [9216,18432) -> u32 [4608,9216)
  { unsigned int* l32 = (unsigned int*)lds_;
    for (int i=4608+tid; i<9216; i+=768) l32[i]=0u; }

  // S and S^2 frags for this wave's (sup, mt) -- core waves only
  const int sup = (w>>2)&1, mt = w&3;
  short8 sfA[4], sfB[4];
  if (core){
#pragma unroll
    for (int kt=0;kt<2;kt++)
#pragma unroll
      for (int pl=0;pl<2;pl++){
        const size_t o = (size_t)((((sup*2+pl)*4+mt)*2+kt)*512 + ln*8);
        sfA[kt*2+pl] = *(const short8*)(frags + o);
        sfB[kt*2+pl] = *(const short8*)(frags + WSF_S2 + o);
      }
  }

  // gate role (core waves): rows 16*mo..16*(mo+2)-1, col block ntg
  const bool lo = (w < 4);
  const int mo = lo ? 0 : 2, ntg = w & 3;
  const int gcol = 16*ntg + fc;

  const unsigned short* WGf = frags + (role? WSF_WG1 : WSF_WG0);
  const unsigned short* WCf = frags + (role? WSF_WC1 : WSF_WC0);
  const float* bg = role? bg1 : bg0;
  const float* bc = role? bc1 : bc0;
  const float brv = bg[gcol];
  const float buv = bg[64+gcol];
  const float bcv = bc[gcol];

  int tl = 0;
  if (role){ tl = seq_lengths[b]-1; tl = tl<0?0:(tl>127?127:tl); }

  float4v h_old[2], uv[2], gaccR[2], gaccU[2], gaccC[2];
#pragma unroll
  for (int i=0;i<2;i++) h_old[i]=(float4v){0.f,0.f,0.f,0.f};

  const int node8 = tid>>3, f08 = (tid&7)*8;
  float4v v_nxt0 = {0.f,0.f,0.f,0.f}, v_nxt1 = {0.f,0.f,0.f,0.f};
  __syncthreads();

  // ---- prologue: XP <- step 0 ----
  if (role==0){
    if (core){
      const float* s0 = input_seq + (((size_t)b*128 + 0)*64 + node8)*64 + f08;
      float4v a0 = *(const float4v*)(s0);
      float4v a1 = *(const float4v*)(s0+4);
      xp_write_pk(lds_, node8, f08, a0, a1);
      const float* s1 = input_seq + (((size_t)b*128 + 1)*64 + node8)*64 + f08;
      v_nxt0 = *(const float4v*)(s1); v_nxt1 = *(const float4v*)(s1+4);
    }
    __syncthreads();
  } else {
    if (tid==0){
      while (__hip_atomic_load(&flags[0], __ATOMIC_ACQUIRE, __HIP_MEMORY_SCOPE_AGENT) != 1)
        __builtin_amdgcn_s_sleep(1);
      __threadfence();
    }
    __syncthreads();
    if (core){
      const unsigned int* sl = slots + ((size_t)(b*16 + 0))*4096 + (w*64+ln)*8;
#pragma unroll
      for (int i=0;i<2;i++){
        uint4v v = *(const uint4v*)(sl + i*4);
#pragma unroll
        for (int r=0;r<4;r++){
          const int o = XP + (16*(mo+i)+4*qd+r)*72 + gcol;
          lds_[o] = (unsigned short)(v[r] & 0xffffu);
          lds_[o+PLO] = (unsigned short)(v[r] >> 16);
        }
      }
    }
    __syncthreads();
    if (tid==0)
      __hip_atomic_store(done, 1, __ATOMIC_RELEASE, __HIP_MEMORY_SCOPE_AGENT);
  }

#pragma unroll 1
  for (int t=0; t<128; ++t){
    // ---- ph2: P1 r ----
    p1_group(lds_, WGf, 0, XP, HP, brv, gaccR, w, ln, fc, qd);
    __syncthreads();
    // ---- ph3: P2 r (Z_r) ----
    if (core) p2_fused(lds_, sfA, sfB, sup, mt, fc, qd);
    __syncthreads();

    // ---- ph4: P1 u + gate r (rh -> RH plane, core waves) ----
    p1_group(lds_, WGf, 1, XP, HP, buv, gaccU, w, ln, fc, qd);
    if (core){
      float4v pre[2]; read_pre(lds_, gaccR, pre, mo, ntg, fc, qd);
      ushort4v oh[2], ol[2];
#pragma unroll
      for (int i=0;i<2;i++){
        float4v rh;
#pragma unroll
        for (int r=0;r<4;r++){
          float rv = 1.f/(1.f+__expf(-pre[i][r]));
          rh[r] = rv*h_old[i][r];
        }
        unsigned int h0,h1,l0,l1;
        cvt_hilo_pk(rh, h0,h1, l0,l1);
        oh[i][0]=(unsigned short)h0; oh[i][1]=(unsigned short)(h0>>16);
        oh[i][2]=(unsigned short)h1; oh[i][3]=(unsigned short)(h1>>16);
        ol[i][0]=(unsigned short)l0; ol[i][1]=(unsigned short)(l0>>16);
        ol[i][2]=(unsigned short)l1; ol[i][3]=(unsigned short)(l1>>16);
      }
      scatter_plane(lds_, RH, mo, ntg, fc, qd, oh, ol);
    }
    __syncthreads();
    // ---- ph5: P2 u (Z_u overwrites Z_r, consumed) ----
    if (core) p2_fused(lds_, sfA, sfB, sup, mt, fc, qd);
    __syncthreads();

    // ---- ph6: P1 c (A = XP | RH) + gate u ----
    p1_group(lds_, WCf, 0, XP, RH, bcv, gaccC, w, ln, fc, qd);
    if (core){
      float4v pre[2]; read_pre(lds_, gaccU, pre, mo, ntg, fc, qd);
#pragma unroll
      for (int i=0;i<2;i++)
#pragma unroll
        for (int r=0;r<4;r++) uv[i][r] = 1.f/(1.f+__expf(-pre[i][r]));
    }
    __syncthreads();

    // ---- ph7: P2 c  (+ producer: XP(t+1) write, done-spin;
    //                   consumer: flags(t+1)-spin) ----
    if (role==0){
      if (core && t<127) xp_write_pk(lds_, node8, f08, v_nxt0, v_nxt1);
      if (core) p2_fused(lds_, sfA, sfB, sup, mt, fc, qd);
      if (tid==0 && t>=16){
        while ((int)__hip_atomic_load(done, __ATOMIC_ACQUIRE, __HIP_MEMORY_SCOPE_AGENT) < t-15)
          __builtin_amdgcn_s_sleep(1);
      }
    } else {
      if (core) p2_fused(lds_, sfA, sfB, sup, mt, fc, qd);
      if (tid==0 && t<127){
        while (__hip_atomic_load(&flags[t+1], __ATOMIC_ACQUIRE, __HIP_MEMORY_SCOPE_AGENT) != t+2)
          __builtin_amdgcn_s_sleep(1);
        __threadfence();
      }
    }
    __syncthreads();

    // ---- ph8: update + IO (core waves; loads issued first to hide latency) ----
    if (core){
      uint4v sv0, sv1;
      sv0[0]=0;sv0[1]=0;sv0[2]=0;sv0[3]=0; sv1=sv0;
      if (role && t<127){
        const unsigned int* sl = slots + ((size_t)(b*16 + ((t+1)&15)))*4096 + (w*64+ln)*8;
        sv0 = *(const uint4v*)(sl);
        sv1 = *(const uint4v*)(sl + 4);
      }
      if (role==0 && t<126){
        const float* s2 = input_seq + (((size_t)b*128 + (t+2))*64 + node8)*64 + f08;
        v_nxt0 = *(const float4v*)(s2); v_nxt1 = *(const float4v*)(s2+4);
      }
      // update (scalar RNE cvt: capb/hi path)
      float4v pre[2]; read_pre(lds_, gaccC, pre, mo, ntg, fc, qd);
      ushort4v oh[2], ol[2];
#pragma unroll
      for (int i=0;i<2;i++){
        float4v hn;
#pragma unroll
        for (int r=0;r<4;r++){
          float x = fminf(pre[i][r], 15.f);
          float e = __expf(2.f*x);
          float cv = (e-1.f)/(e+1.f);
          float u1 = uv[i][r];
          hn[r] = u1*h_old[i][r] + (1.f-u1)*cv;
        }
        h_old[i] = hn;
        cvt_hilo(hn, oh[i], ol[i]);
      }
      scatter_plane(lds_, HP, mo, ntg, fc, qd, oh, ol);
      if (role==0){
        unsigned int* sl = slots + ((size_t)(b*16 + (t&15)))*4096 + (w*64+ln)*8;
#pragma unroll
        for (int i=0;i<2;i++){
          uint4v pk;
#pragma unroll
          for (int r=0;r<4;r++)
            pk[r] = (unsigned int)oh[i][r] | ((unsigned int)ol[i][r] << 16);
          *(uint4v*)(sl + i*4) = pk;
        }
      } else {
        if (t==tl){
#pragma unroll
          for (int i=0;i<2;i++)
#pragma unroll
            for (int r=0;r<4;r++)
              capb[(16*(mo+i)+4*qd+r)*64 + gcol] = oh[i][r];
        }
        if (t<127){
#pragma unroll
          for (int i=0;i<2;i++){
            uint4v v = i ? sv1 : sv0;
#pragma unroll
            for (int r=0;r<4;r++){
              const int o = XP + (16*(mo+i)+4*qd+r)*72 + gcol;
              lds_[o] = (unsigned short)(v[r] & 0xffffu);
              lds_[o+PLO] = (unsigned short)(v[r] >> 16);
            }
          }
        }
      }
    }
    __syncthreads();
    if (tid==0){
      if (role==0){
        __threadfence();
        __hip_atomic_store(&flags[t], t+1, __ATOMIC_RELEASE, __HIP_MEMORY_SCOPE_AGENT);
      } else if (t<127){
        __hip_atomic_store(done, t+2, __ATOMIC_RELEASE, __HIP_MEMORY_SCOPE_AGENT);
      }
    }
  }

  if (role==0) return;

  __threadfence();
  __syncthreads();
  // epilogue (consumer): logits = relu(last_h2) @ Wp + bp; max over nodes
  float* sc = (float*)lds_;
  if (tid < 64){
    const unsigned short* hpx = capb + tid*64;
    float4v acc = {bp[0], bp[1], bp[2], bp[3]};
#pragma unroll 1
    for (int ch = 0; ch < 64; ++ch){
      float h = fmaxf(bf2f(hpx[ch]), 0.f);
      const float4v wr = *(const float4v*)(Wp + ch*4);
      acc += h * wr;
    }
    sc[tid*4+0]=acc[0]; sc[tid*4+1]=acc[1]; sc[tid*4+2]=acc[2]; sc[tid*4+3]=acc[3];
  }
  __syncthreads();
  if (tid < 4){
    float m = sc[tid];
#pragma unroll 1
    for (int n=1;n<64;n++) m = fmaxf(m, sc[n*4 + tid]);
    out[b*4 + tid] = m;
  }
}

// ---- S^2 (fp32) into ws scratch ----
__global__ void __launch_bounds__(256)
dcrnn_sq(const float* __restrict__ S0, const float* __restrict__ S1,
         float* __restrict__ sqs)
{
  const float* S = blockIdx.x ? S1 : S0;
  float* D = sqs + blockIdx.x*4096;
  const int i = threadIdx.x >> 2, j0 = (threadIdx.x & 3)*16;
  float acc[16];
#pragma unroll
  for (int j=0;j<16;j++) acc[j]=0.f;
#pragma unroll 4
  for (int k=0;k<64;k++){
    float s = S[i*64+k];
    const float* row = S + k*64 + j0;
#pragma unroll
    for (int j=0;j<16;j++) acc[j] += s*row[j];
  }
#pragma unroll
  for (int j=0;j<16;j++) D[i*64+j0+j]=acc[j];
}

// ---- prep: S, S^2 frags (A-layout) + folded W frags (B-layout), hi/lo ----
__global__ void __launch_bounds__(256)
dcrnn_prep(const float* __restrict__ S0, const float* __restrict__ S1,
           const float* __restrict__ Wg0, const float* __restrict__ Wc0,
           const float* __restrict__ Wg1, const float* __restrict__ Wc1,
           const float* __restrict__ sqs, unsigned short* __restrict__ frags)
{
  const int uid = blockIdx.x*256 + threadIdx.x;
  if (uid >= 65536) return;
  short8 o;
  unsigned short* dst;
  if (uid < 4096){
    int r = uid & 2047;
    const bool issq = uid >= 2048;
    const int lane = r & 63; r >>= 6;
    const int kt = r & 1; r >>= 1;
    const int Mt = r & 3; r >>= 2;
    const int pl = r & 1; r >>= 1;
    const float* S = issq ? (sqs + r*4096) : (r ? S1 : S0);
    const int m  = 16*Mt + (lane & 15);
    const int k0 = 32*kt + 8*(lane >> 4);
#pragma unroll
    for (int j=0;j<8;j++){
      float v = S[m*64 + k0 + j];
      unsigned short hi = f2bf(v);
      o[j] = (short)(pl ? f2bf(v - bf2f(hi)) : hi);
    }
    dst = frags + (issq ? WSF_S2 : 0) + (size_t)(uid & 2047)*8;
  } else {
    int u2 = uid - 4096;
    const float* W; int wld; size_t base;
    if      (u2 < 20480){ W = Wg0; wld = 128; base = WSF_WG0; }
    else if (u2 < 30720){ W = Wc0; wld = 64;  base = WSF_WC0; u2 -= 20480; }
    else if (u2 < 51200){ W = Wg1; wld = 128; base = WSF_WG1; u2 -= 30720; }
    else                { W = Wc1; wld = 64;  base = WSF_WC1; u2 -= 51200; }
    const int lane = u2 & 63;
    const int pl   = (u2 >> 6) & 1;
    const int rest = u2 >> 7;                 // ((grp*5+j)*4+nt)*4+kt
    const int kt = rest & 3;
    const int nt = (rest >> 2) & 3;
    const int j  = (rest >> 4) % 5;
    const int grp= (rest >> 4) / 5;
    const int col = grp*64 + 16*nt + (lane & 15);
    const int k0  = 32*kt + 8*(lane >> 4);
#pragma unroll
    for (int jj=0;jj<8;jj++){
      const int k = k0 + jj;
      float v;
      if (j == 0)
        v = W[(size_t)k*wld + col] - W[(size_t)(256+k)*wld + col] - W[(size_t)(512+k)*wld + col];
      else {
        v = W[(size_t)(j*128 + k)*wld + col];
        if (j == 2 || j == 4) v *= 2.f;
      }
      unsigned short hi = f2bf(v);
      o[jj] = (short)(pl ? f2bf(v - bf2f(hi)) : hi);
    }
    dst = frags + base + (size_t)u2*8;
  }
  *(short8*)dst = o;
}

extern "C" void kernel_launch(void* const* d_in, const int* in_sizes, int n_in,
                              void* d_out, int out_size, void* d_ws, size_t ws_size,
                              hipStream_t stream) {
  const float* input_seq   = (const float*)d_in[0];
  const int*   seq_lengths = (const int*)  d_in[1];
  const float* S0  = (const float*)d_in[2];
  const float* S1  = (const float*)d_in[3];
  const float* Wg0 = (const float*)d_in[4];
  const float* bg0 = (const float*)d_in[5];
  const float* Wc0 = (const float*)d_in[6];
  const float* bc0 = (const float*)d_in[7];
  const float* Wg1 = (const float*)d_in[8];
  const float* bg1 = (const float*)d_in[9];
  const float* Wc1 = (const float*)d_in[10];
  const float* bc1 = (const float*)d_in[11];
  const float* Wp  = (const float*)d_in[12];
  const float* bp  = (const float*)d_in[13];

  unsigned short* ws = (unsigned short*)d_ws;
  float* sqs = (float*)(ws + WSF_SQS);

  dcrnn_sq<<<dim3(2), dim3(256), 0, stream>>>(S0, S1, sqs);
  dcrnn_prep<<<dim3(256), dim3(256), 0, stream>>>(S0, S1, Wg0, Wc0, Wg1, Wc1, sqs, ws);

  (void)hipFuncSetAttribute((const void*)dcrnn_main,
                            hipFuncAttributeMaxDynamicSharedMemorySize, LDS_BYTES);
  dcrnn_main<<<dim3(64), dim3(768), LDS_BYTES, stream>>>(
      input_seq, seq_lengths, bg0, bc0, bg1, bc1, Wp, bp, ws, (float*)d_out);
}

// Round 12
// 2434.909 us; speedup vs baseline: 1.3508x; 1.3508x over previous
//
#include <hip/hip_runtime.h>
#include <stdint.h>

// R16 = R14 restored verbatim (proven 2441us; best verified).
// R15 post-mortem closed the occupancy question: 4 waves/SIMD (R7, R8) and
// 3 waves/SIMD (R15) ALL spill (WRITE_SIZE +150-250MB scratch signature) --
// this kernel's P1 live set fits only at 2 waves/SIMD (256-reg budget).
// R14 structure: 512 thr, 7 barriers/step (acquire merged into ph7/ph8),
// Mt-split balanced P1 (120/120), packed cvt_pk bf16 conversion, tid0-only
// spins, compile-time register indices throughout.

typedef short short8 __attribute__((ext_vector_type(8)));
typedef float float4v __attribute__((ext_vector_type(4)));
typedef unsigned short ushort4v __attribute__((ext_vector_type(4)));
typedef unsigned int uint4v __attribute__((ext_vector_type(4)));
typedef unsigned int uint2v __attribute__((ext_vector_type(2)));

#define MF(a,b,c) __builtin_amdgcn_mfma_f32_16x16x32_bf16(a,b,c,0,0,0)

__device__ __forceinline__ unsigned short f2bf(float v){
  unsigned int x = __builtin_bit_cast(unsigned int, v);
  x += 0x7FFFu + ((x >> 16) & 1u);
  return (unsigned short)(x >> 16);
}
__device__ __forceinline__ float bf2f(unsigned short h){
  unsigned int x = ((unsigned int)h) << 16;
  return __builtin_bit_cast(float, x);
}
__device__ __forceinline__ void cvt_hilo(const float4v v, ushort4v& oh, ushort4v& ol){
#pragma unroll
  for (int r=0;r<4;r++){ unsigned short h=f2bf(v[r]); oh[r]=h; ol[r]=f2bf(v[r]-bf2f(h)); }
}

// packed conversion: 2 floats -> 1 u32 of 2xbf16 (T12 recipe; no builtin)
__device__ __forceinline__ unsigned int cvtpk(float a, float b){
  unsigned int r;
  asm("v_cvt_pk_bf16_f32 %0, %1, %2" : "=v"(r) : "v"(a), "v"(b));
  return r;
}
__device__ __forceinline__ float bcf(unsigned int x){
  return __builtin_bit_cast(float, x);
}
__device__ __forceinline__ void cvt_hilo_pk(const float4v v,
    unsigned int& h0, unsigned int& h1, unsigned int& l0, unsigned int& l1){
  h0 = cvtpk(v[0], v[1]);
  h1 = cvtpk(v[2], v[3]);
  l0 = cvtpk(v[0]-bcf(h0<<16), v[1]-bcf(h0&0xffff0000u));
  l1 = cvtpk(v[2]-bcf(h1<<16), v[3]-bcf(h1&0xffff0000u));
}

// ---- LDS (u16). pair planes: hi at base, lo at +PLO; row stride 72 u16 ----
#define PLO 4608
#define XP  0
#define HP  9216
#define RH  18432
#define YS0 27648   // YA sup0 (j1)
#define YS1 36864   // YB sup0 (j2, pre-scaled 2x)
#define YS2 46080   // YA sup1 (j3)
#define YS3 55296   // YB sup1 (j4, pre-scaled 2x)
#define Z0F 32256   // f32 index (u16 64512), stride 68 floats
#define Z1F 36608
#define LDS_BYTES 163840

// ---- ws offsets (u16) ----
#define WSF_S2   16384
#define WSF_WG0  32768
#define WSF_WC0  196608
#define WSF_WG1  278528
#define WSF_WC1  442368
#define WSF_CAP  524288
#define WSF_FLAG 655360   // int flags[32][128]
#define WSF_DONE 663552   // int done[32]
#define WSF_SLOT 663616   // 32*16 slots * 4096 u32 (hi | lo<<16)
#define WSF_SQS  4857920  // 2*4096 f32 scratch (S0^2, S1^2)

#define TB(grp,j,nt) ((((grp)*5+(j))*4+(nt))*4)

__device__ __forceinline__ void store_Y(unsigned short* lds_, int buf, int nt,
                                        int fc, int qd, const float4v* acc){
#pragma unroll
  for (int Mt=0;Mt<4;Mt++){
    unsigned int h0,h1,l0,l1;
    cvt_hilo_pk(acc[Mt],h0,h1,l0,l1);
    const int o = buf + (16*nt+fc)*72 + 16*Mt + 4*qd;   // o%4==0 -> 8B aligned
    uint2v hv; hv[0]=h0; hv[1]=h1;
    uint2v lv; lv[0]=l0; lv[1]=l1;
    *(uint2v*)(lds_+o)=hv; *(uint2v*)(lds_+o+PLO)=lv;
  }
}

__device__ __forceinline__ void xp_write_pk(unsigned short* lds_, int node, int f0,
                                            float4v a0, float4v a1){
  unsigned int h0,h1,h2,h3, l0,l1,l2,l3;
  cvt_hilo_pk(a0, h0,h1, l0,l1);
  cvt_hilo_pk(a1, h2,h3, l2,l3);
  uint4v hv; hv[0]=h0; hv[1]=h1; hv[2]=h2; hv[3]=h3;
  uint4v lv; lv[0]=l0; lv[1]=l1; lv[2]=l2; lv[3]=l3;
  *(uint4v*)(lds_ + XP + node*72 + f0) = hv;        // 16B aligned
  *(uint4v*)(lds_ + XP + PLO + node*72 + f0) = lv;
}

// P1: one A pass -> gacc (j0,+bias; this wave's 2 Mt rows) + YA/YB tiles (4 Mt)
__device__ __forceinline__ void p1_group(unsigned short* lds_,
    const unsigned short* __restrict__ wfr, int grp, int p0, int p1,
    float bias, float4v* gacc, int w, int ln, int fc, int qd)
{
  const int nt = w & 3;
  const bool lo = (w < 4);
  float4v aY0[4], aY1[4];
#pragma unroll
  for (int Mt=0;Mt<4;Mt++){
    aY0[Mt]=(float4v){0.f,0.f,0.f,0.f};
    aY1[Mt]=(float4v){0.f,0.f,0.f,0.f};
  }
#pragma unroll
  for (int i=0;i<2;i++) gacc[i]=(float4v){bias,bias,bias,bias};
  const int tbG = TB(grp,0,nt);
  const int tbA = lo ? TB(grp,1,nt) : TB(grp,2,nt);
  const int tbB = lo ? TB(grp,3,nt) : TB(grp,4,nt);
#pragma unroll
  for (int kt=0;kt<4;kt++){
    const int pb = (kt<2)? p0 : p1;
    short8 ah[4], al[4];
#pragma unroll
    for (int Mt=0;Mt<4;Mt++){
      const int o = pb + (16*Mt+fc)*72 + 32*(kt&1) + 8*qd;
      ah[Mt]=*(const short8*)(lds_+o);
      al[Mt]=*(const short8*)(lds_+o+PLO);
    }
    {
      const unsigned short* wb = wfr + (size_t)((tbG+kt)*2)*512 + ln*8;
      short8 bh=*(const short8*)wb, bl=*(const short8*)(wb+512);
      // compile-time indices only (runtime idx demotes ah/al to scratch)
      if (lo){
        gacc[0]=MF(ah[0],bh,gacc[0]); gacc[0]=MF(ah[0],bl,gacc[0]);
        gacc[0]=MF(al[0],bh,gacc[0]);
        gacc[1]=MF(ah[1],bh,gacc[1]); gacc[1]=MF(ah[1],bl,gacc[1]);
        gacc[1]=MF(al[1],bh,gacc[1]);
      } else {
        gacc[0]=MF(ah[2],bh,gacc[0]); gacc[0]=MF(ah[2],bl,gacc[0]);
        gacc[0]=MF(al[2],bh,gacc[0]);
        gacc[1]=MF(ah[3],bh,gacc[1]); gacc[1]=MF(ah[3],bl,gacc[1]);
        gacc[1]=MF(al[3],bh,gacc[1]);
      }
    }
    {
      const unsigned short* wb = wfr + (size_t)((tbA+kt)*2)*512 + ln*8;
      short8 bh=*(const short8*)wb, bl=*(const short8*)(wb+512);
#pragma unroll
      for (int Mt=0;Mt<4;Mt++){
        aY0[Mt]=MF(ah[Mt],bh,aY0[Mt]); aY0[Mt]=MF(ah[Mt],bl,aY0[Mt]);
        aY0[Mt]=MF(al[Mt],bh,aY0[Mt]);
      }
    }
    {
      const unsigned short* wb = wfr + (size_t)((tbB+kt)*2)*512 + ln*8;
      short8 bh=*(const short8*)wb, bl=*(const short8*)(wb+512);
#pragma unroll
      for (int Mt=0;Mt<4;Mt++){
        aY1[Mt]=MF(ah[Mt],bh,aY1[Mt]); aY1[Mt]=MF(ah[Mt],bl,aY1[Mt]);
        aY1[Mt]=MF(al[Mt],bh,aY1[Mt]);
      }
    }
  }
  store_Y(lds_, lo? YS0 : YS1, nt, fc, qd, aY0);
  store_Y(lds_, lo? YS2 : YS3, nt, fc, qd, aY1);
}

// P2 fused: Z_sup = S_sup @ YA_sup + S_sup^2 @ YB_sup  -> fp32 Z plane
__device__ __forceinline__ void p2_fused(unsigned short* lds_,
    const short8* sfA, const short8* sfB, int sup, int mt, int fc, int qd)
{
  const int ya = sup? YS2 : YS0;
  const int yb = sup? YS3 : YS1;
  float* zf = (float*)lds_ + (sup? Z1F : Z0F);
#pragma unroll
  for (int nt=0;nt<4;nt++){
    float4v acc = {0.f,0.f,0.f,0.f};
#pragma unroll
    for (int kt=0;kt<2;kt++){
      {
        const int bo = ya + (16*nt+fc)*72 + 32*kt + 8*qd;
        short8 bh=*(const short8*)(lds_+bo), bl=*(const short8*)(lds_+bo+PLO);
        acc=MF(sfA[kt*2+0],bh,acc); acc=MF(sfA[kt*2+0],bl,acc); acc=MF(sfA[kt*2+1],bh,acc);
      }
      {
        const int bo = yb + (16*nt+fc)*72 + 32*kt + 8*qd;
        short8 bh=*(const short8*)(lds_+bo), bl=*(const short8*)(lds_+bo+PLO);
        acc=MF(sfB[kt*2+0],bh,acc); acc=MF(sfB[kt*2+0],bl,acc); acc=MF(sfB[kt*2+1],bh,acc);
      }
    }
    *(float4v*)(zf + (16*nt+fc)*68 + 16*mt + 4*qd) = acc;
  }
}

__device__ __forceinline__ void read_pre(const unsigned short* lds_,
    const float4v* gacc, float4v* pre, int mo, int ntg, int fc, int qd)
{
  const float* lf = (const float*)lds_;
#pragma unroll
  for (int i=0;i<2;i++){
    const int Mt = mo+i;
    float4v za = *(const float4v*)(lf + Z0F + (16*ntg+fc)*68 + 16*Mt + 4*qd);
    float4v zb = *(const float4v*)(lf + Z1F + (16*ntg+fc)*68 + 16*Mt + 4*qd);
    pre[i] = gacc[i] + za + zb;
  }
}

__device__ __forceinline__ void scatter_plane(unsigned short* lds_, int plane,
    int mo, int ntg, int fc, int qd, const ushort4v* oh, const ushort4v* ol)
{
#pragma unroll
  for (int i=0;i<2;i++){
#pragma unroll
    for (int r=0;r<4;r++){
      const int o = plane + (16*(mo+i)+4*qd+r)*72 + 16*ntg+fc;
      lds_[o] = oh[i][r]; lds_[o+PLO] = ol[i][r];
    }
  }
}

__global__ void __launch_bounds__(512, 2)
dcrnn_main(const float* __restrict__ input_seq, const int* __restrict__ seq_lengths,
           const float* __restrict__ bg0, const float* __restrict__ bc0,
           const float* __restrict__ bg1, const float* __restrict__ bc1,
           const float* __restrict__ Wp, const float* __restrict__ bp,
           unsigned short* __restrict__ ws, float* __restrict__ out)
{
  extern __shared__ unsigned short lds_[];
  const int tid = threadIdx.x;
  const int w = tid>>6, ln = tid&63, fc = ln&15, qd = ln>>4;
  const int role = blockIdx.x >> 5;   // 0 = layer0 producer, 1 = layer1 consumer
  const int b = blockIdx.x & 31;

  const unsigned short* frags = ws;
  int* flags = (int*)(ws + WSF_FLAG) + b*128;
  int* done  = (int*)(ws + WSF_DONE) + b;
  unsigned short* capb = ws + WSF_CAP + (size_t)b*4096;
  unsigned int* slots = (unsigned int*)(ws + WSF_SLOT);

  // zero HP pair: u16 [9216,18432) -> u32 [4608,9216)
  { unsigned int* l32 = (unsigned int*)lds_;
    for (int i=4608+tid; i<9216; i+=512) l32[i]=0u; }

  // S and S^2 frags for this wave's (sup, mt)
  const int sup = (w>>2)&1, mt = w&3;
  short8 sfA[4], sfB[4];
#pragma unroll
  for (int kt=0;kt<2;kt++)
#pragma unroll
    for (int pl=0;pl<2;pl++){
      const size_t o = (size_t)((((sup*2+pl)*4+mt)*2+kt)*512 + ln*8);
      sfA[kt*2+pl] = *(const short8*)(frags + o);
      sfB[kt*2+pl] = *(const short8*)(frags + WSF_S2 + o);
    }

  // gate role: every wave owns (rows 16*mo..16*(mo+2)-1, col block ntg)
  const bool lo = (w < 4);
  const int mo = lo ? 0 : 2, ntg = w & 3;
  const int gcol = 16*ntg + fc;

  const unsigned short* WGf = frags + (role? WSF_WG1 : WSF_WG0);
  const unsigned short* WCf = frags + (role? WSF_WC1 : WSF_WC0);
  const float* bg = role? bg1 : bg0;
  const float* bc = role? bc1 : bc0;
  const float brv = bg[gcol];
  const float buv = bg[64+gcol];
  const float bcv = bc[gcol];

  int tl = 0;
  if (role){ tl = seq_lengths[b]-1; tl = tl<0?0:(tl>127?127:tl); }

  float4v h_old[2], uv[2], gaccR[2], gaccU[2], gaccC[2];
#pragma unroll
  for (int i=0;i<2;i++) h_old[i]=(float4v){0.f,0.f,0.f,0.f};

  const int node8 = tid>>3, f08 = (tid&7)*8;
  float4v v_nxt0 = {0.f,0.f,0.f,0.f}, v_nxt1 = {0.f,0.f,0.f,0.f};
  __syncthreads();

  // ---- prologue: XP <- step 0 ----
  if (role==0){
    const float* s0 = input_seq + (((size_t)b*128 + 0)*64 + node8)*64 + f08;
    float4v a0 = *(const float4v*)(s0);
    float4v a1 = *(const float4v*)(s0+4);
    xp_write_pk(lds_, node8, f08, a0, a1);
    const float* s1 = input_seq + (((size_t)b*128 + 1)*64 + node8)*64 + f08;
    v_nxt0 = *(const float4v*)(s1); v_nxt1 = *(const float4v*)(s1+4);
    __syncthreads();
  } else {
    if (tid==0){
      while (__hip_atomic_load(&flags[0], __ATOMIC_ACQUIRE, __HIP_MEMORY_SCOPE_AGENT) != 1)
        __builtin_amdgcn_s_sleep(1);
      __threadfence();
    }
    __syncthreads();
    {
      const unsigned int* sl = slots + ((size_t)(b*16 + 0))*4096 + (w*64+ln)*8;
#pragma unroll
      for (int i=0;i<2;i++){
        uint4v v = *(const uint4v*)(sl + i*4);
#pragma unroll
        for (int r=0;r<4;r++){
          const int o = XP + (16*(mo+i)+4*qd+r)*72 + gcol;
          lds_[o] = (unsigned short)(v[r] & 0xffffu);
          lds_[o+PLO] = (unsigned short)(v[r] >> 16);
        }
      }
    }
    __syncthreads();
    if (tid==0)
      __hip_atomic_store(done, 1, __ATOMIC_RELEASE, __HIP_MEMORY_SCOPE_AGENT);
  }

#pragma unroll 1
  for (int t=0; t<128; ++t){
    // ---- ph2: P1 r ----
    p1_group(lds_, WGf, 0, XP, HP, brv, gaccR, w, ln, fc, qd);
    __syncthreads();
    // ---- ph3: P2 r (Z_r) ----
    p2_fused(lds_, sfA, sfB, sup, mt, fc, qd);
    __syncthreads();

    // ---- ph4: P1 u + gate r (rh -> RH plane, all 8 waves) ----
    p1_group(lds_, WGf, 1, XP, HP, buv, gaccU, w, ln, fc, qd);
    {
      float4v pre[2]; read_pre(lds_, gaccR, pre, mo, ntg, fc, qd);
      ushort4v oh[2], ol[2];
#pragma unroll
      for (int i=0;i<2;i++){
        float4v rh;
#pragma unroll
        for (int r=0;r<4;r++){
          float rv = 1.f/(1.f+__expf(-pre[i][r]));
          rh[r] = rv*h_old[i][r];
        }
        unsigned int h0,h1,l0,l1;
        cvt_hilo_pk(rh, h0,h1, l0,l1);
        oh[i][0]=(unsigned short)h0; oh[i][1]=(unsigned short)(h0>>16);
        oh[i][2]=(unsigned short)h1; oh[i][3]=(unsigned short)(h1>>16);
        ol[i][0]=(unsigned short)l0; ol[i][1]=(unsigned short)(l0>>16);
        ol[i][2]=(unsigned short)l1; ol[i][3]=(unsigned short)(l1>>16);
      }
      scatter_plane(lds_, RH, mo, ntg, fc, qd, oh, ol);
    }
    __syncthreads();
    // ---- ph5: P2 u (Z_u overwrites Z_r, consumed) ----
    p2_fused(lds_, sfA, sfB, sup, mt, fc, qd);
    __syncthreads();

    // ---- ph6: P1 c (A = XP | RH) + gate u ----
    p1_group(lds_, WCf, 0, XP, RH, bcv, gaccC, w, ln, fc, qd);
    {
      float4v pre[2]; read_pre(lds_, gaccU, pre, mo, ntg, fc, qd);
#pragma unroll
      for (int i=0;i<2;i++)
#pragma unroll
        for (int r=0;r<4;r++) uv[i][r] = 1.f/(1.f+__expf(-pre[i][r]));
    }
    __syncthreads();

    // ---- ph7: P2 c  (+ producer: XP(t+1) write, done-spin;
    //                   consumer: flags(t+1)-spin) ----
    if (role==0){
      if (t<127) xp_write_pk(lds_, node8, f08, v_nxt0, v_nxt1);
      p2_fused(lds_, sfA, sfB, sup, mt, fc, qd);
      if (tid==0 && t>=16){
        while ((int)__hip_atomic_load(done, __ATOMIC_ACQUIRE, __HIP_MEMORY_SCOPE_AGENT) < t-15)
          __builtin_amdgcn_s_sleep(1);
      }
    } else {
      p2_fused(lds_, sfA, sfB, sup, mt, fc, qd);
      if (tid==0 && t<127){
        while (__hip_atomic_load(&flags[t+1], __ATOMIC_ACQUIRE, __HIP_MEMORY_SCOPE_AGENT) != t+2)
          __builtin_amdgcn_s_sleep(1);
        __threadfence();
      }
    }
    __syncthreads();

    // ---- ph8: update + IO (slot/input loads issued first to hide latency) ----
    {
      uint4v sv0, sv1;
      sv0[0]=0;sv0[1]=0;sv0[2]=0;sv0[3]=0; sv1=sv0;
      if (role && t<127){
        const unsigned int* sl = slots + ((size_t)(b*16 + ((t+1)&15)))*4096 + (w*64+ln)*8;
        sv0 = *(const uint4v*)(sl);
        sv1 = *(const uint4v*)(sl + 4);
      }
      if (role==0 && t<126){
        const float* s2 = input_seq + (((size_t)b*128 + (t+2))*64 + node8)*64 + f08;
        v_nxt0 = *(const float4v*)(s2); v_nxt1 = *(const float4v*)(s2+4);
      }
      // update (all 8 waves; scalar RNE cvt: capb/hi path)
      float4v pre[2]; read_pre(lds_, gaccC, pre, mo, ntg, fc, qd);
      ushort4v oh[2], ol[2];
#pragma unroll
      for (int i=0;i<2;i++){
        float4v hn;
#pragma unroll
        for (int r=0;r<4;r++){
          float x = fminf(pre[i][r], 15.f);
          float e = __expf(2.f*x);
          float cv = (e-1.f)/(e+1.f);
          float u1 = uv[i][r];
          hn[r] = u1*h_old[i][r] + (1.f-u1)*cv;
        }
        h_old[i] = hn;
        cvt_hilo(hn, oh[i], ol[i]);
      }
      scatter_plane(lds_, HP, mo, ntg, fc, qd, oh, ol);
      if (role==0){
        unsigned int* sl = slots + ((size_t)(b*16 + (t&15)))*4096 + (w*64+ln)*8;
#pragma unroll
        for (int i=0;i<2;i++){
          uint4v pk;
#pragma unroll
          for (int r=0;r<4;r++)
            pk[r] = (unsigned int)oh[i][r] | ((unsigned int)ol[i][r] << 16);
          *(uint4v*)(sl + i*4) = pk;
        }
      } else {
        if (t==tl){
#pragma unroll
          for (int i=0;i<2;i++)
#pragma unroll
            for (int r=0;r<4;r++)
              capb[(16*(mo+i)+4*qd+r)*64 + gcol] = oh[i][r];
        }
        if (t<127){
#pragma unroll
          for (int i=0;i<2;i++){
            uint4v v = i ? sv1 : sv0;
#pragma unroll
            for (int r=0;r<4;r++){
              const int o = XP + (16*(mo+i)+4*qd+r)*72 + gcol;
              lds_[o] = (unsigned short)(v[r] & 0xffffu);
              lds_[o+PLO] = (unsigned short)(v[r] >> 16);
            }
          }
        }
      }
    }
    __syncthreads();
    if (tid==0){
      if (role==0){
        __threadfence();
        __hip_atomic_store(&flags[t], t+1, __ATOMIC_RELEASE, __HIP_MEMORY_SCOPE_AGENT);
      } else if (t<127){
        __hip_atomic_store(done, t+2, __ATOMIC_RELEASE, __HIP_MEMORY_SCOPE_AGENT);
      }
    }
  }

  if (role==0) return;

  __threadfence();
  __syncthreads();
  // epilogue (consumer): logits = relu(last_h2) @ Wp + bp; max over nodes
  float* sc = (float*)lds_;
  if (tid < 64){
    const unsigned short* hpx = capb + tid*64;
    float4v acc = {bp[0], bp[1], bp[2], bp[3]};
#pragma unroll 1
    for (int ch = 0; ch < 64; ++ch){
      float h = fmaxf(bf2f(hpx[ch]), 0.f);
      const float4v wr = *(const float4v*)(Wp + ch*4);
      acc += h * wr;
    }
    sc[tid*4+0]=acc[0]; sc[tid*4+1]=acc[1]; sc[tid*4+2]=acc[2]; sc[tid*4+3]=acc[3];
  }
  __syncthreads();
  if (tid < 4){
    float m = sc[tid];
#pragma unroll 1
    for (int n=1;n<64;n++) m = fmaxf(m, sc[n*4 + tid]);
    out[b*4 + tid] = m;
  }
}

// ---- S^2 (fp32) into ws scratch ----
__global__ void __launch_bounds__(256)
dcrnn_sq(const float* __restrict__ S0, const float* __restrict__ S1,
         float* __restrict__ sqs)
{
  const float* S = blockIdx.x ? S1 : S0;
  float* D = sqs + blockIdx.x*4096;
  const int i = threadIdx.x >> 2, j0 = (threadIdx.x & 3)*16;
  float acc[16];
#pragma unroll
  for (int j=0;j<16;j++) acc[j]=0.f;
#pragma unroll 4
  for (int k=0;k<64;k++){
    float s = S[i*64+k];
    const float* row = S + k*64 + j0;
#pragma unroll
    for (int j=0;j<16;j++) acc[j] += s*row[j];
  }
#pragma unroll
  for (int j=0;j<16;j++) D[i*64+j0+j]=acc[j];
}

// ---- prep: S, S^2 frags (A-layout) + folded W frags (B-layout), hi/lo ----
__global__ void __launch_bounds__(256)
dcrnn_prep(const float* __restrict__ S0, const float* __restrict__ S1,
           const float* __restrict__ Wg0, const float* __restrict__ Wc0,
           const float* __restrict__ Wg1, const float* __restrict__ Wc1,
           const float* __restrict__ sqs, unsigned short* __restrict__ frags)
{
  const int uid = blockIdx.x*256 + threadIdx.x;
  if (uid >= 65536) return;
  short8 o;
  unsigned short* dst;
  if (uid < 4096){
    int r = uid & 2047;
    const bool issq = uid >= 2048;
    const int lane = r & 63; r >>= 6;
    const int kt = r & 1; r >>= 1;
    const int Mt = r & 3; r >>= 2;
    const int pl = r & 1; r >>= 1;
    const float* S = issq ? (sqs + r*4096) : (r ? S1 : S0);
    const int m  = 16*Mt + (lane & 15);
    const int k0 = 32*kt + 8*(lane >> 4);
#pragma unroll
    for (int j=0;j<8;j++){
      float v = S[m*64 + k0 + j];
      unsigned short hi = f2bf(v);
      o[j] = (short)(pl ? f2bf(v - bf2f(hi)) : hi);
    }
    dst = frags + (issq ? WSF_S2 : 0) + (size_t)(uid & 2047)*8;
  } else {
    int u2 = uid - 4096;
    const float* W; int wld; size_t base;
    if      (u2 < 20480){ W = Wg0; wld = 128; base = WSF_WG0; }
    else if (u2 < 30720){ W = Wc0; wld = 64;  base = WSF_WC0; u2 -= 20480; }
    else if (u2 < 51200){ W = Wg1; wld = 128; base = WSF_WG1; u2 -= 30720; }
    else                { W = Wc1; wld = 64;  base = WSF_WC1; u2 -= 51200; }
    const int lane = u2 & 63;
    const int pl   = (u2 >> 6) & 1;
    const int rest = u2 >> 7;                 // ((grp*5+j)*4+nt)*4+kt
    const int kt = rest & 3;
    const int nt = (rest >> 2) & 3;
    const int j  = (rest >> 4) % 5;
    const int grp= (rest >> 4) / 5;
    const int col = grp*64 + 16*nt + (lane & 15);
    const int k0  = 32*kt + 8*(lane >> 4);
#pragma unroll
    for (int jj=0;jj<8;jj++){
      const int k = k0 + jj;
      float v;
      if (j == 0)
        v = W[(size_t)k*wld + col] - W[(size_t)(256+k)*wld + col] - W[(size_t)(512+k)*wld + col];
      else {
        v = W[(size_t)(j*128 + k)*wld + col];
        if (j == 2 || j == 4) v *= 2.f;
      }
      unsigned short hi = f2bf(v);
      o[jj] = (short)(pl ? f2bf(v - bf2f(hi)) : hi);
    }
    dst = frags + base + (size_t)u2*8;
  }
  *(short8*)dst = o;
}

extern "C" void kernel_launch(void* const* d_in, const int* in_sizes, int n_in,
                              void* d_out, int out_size, void* d_ws, size_t ws_size,
                              hipStream_t stream) {
  const float* input_seq   = (const float*)d_in[0];
  const int*   seq_lengths = (const int*)  d_in[1];
  const float* S0  = (const float*)d_in[2];
  const float* S1  = (const float*)d_in[3];
  const float* Wg0 = (const float*)d_in[4];
  const float* bg0 = (const float*)d_in[5];
  const float* Wc0 = (const float*)d_in[6];
  const float* bc0 = (const float*)d_in[7];
  const float* Wg1 = (const float*)d_in[8];
  const float* bg1 = (const float*)d_in[9];
  const float* Wc1 = (const float*)d_in[10];
  const float* bc1 = (const float*)d_in[11];
  const float* Wp  = (const float*)d_in[12];
  const float* bp  = (const float*)d_in[13];

  unsigned short* ws = (unsigned short*)d_ws;
  float* sqs = (float*)(ws + WSF_SQS);

  dcrnn_sq<<<dim3(2), dim3(256), 0, stream>>>(S0, S1, sqs);
  dcrnn_prep<<<dim3(256), dim3(256), 0, stream>>>(S0, S1, Wg0, Wc0, Wg1, Wc1, sqs, ws);

  (void)hipFuncSetAttribute((const void*)dcrnn_main,
                            hipFuncAttributeMaxDynamicSharedMemorySize, LDS_BYTES);
  dcrnn_main<<<dim3(64), dim3(512), LDS_BYTES, stream>>>(
      input_seq, seq_lengths, bg0, bc0, bg1, bc1, Wp, bp, ws, (float*)d_out);
}